// Round 8
// baseline (431.388 us; speedup 1.0000x reference)
//
#include <hip/hip_runtime.h>

constexpr int NTHR = 256;
constexpr int BW   = 4;      // batches per wave

typedef short  short8 __attribute__((ext_vector_type(8)));  // 8 bf16 (4 VGPRs)
typedef float  f32x4  __attribute__((ext_vector_type(4)));

// factor row offsets per level: L0:0  L1:1  L2:5  L3:21  L4:85  L5:341
// Zero-barrier design: each wave owns BW batches and the whole tree for them.
// All LDS buffers are wave-private (one aliased pool); intra-wave LDS ordering
// is guaranteed by compiler-inserted lgkmcnt waits. No __syncthreads.
//
// Register ledger: (256,3)->80 (256,4)->64 (256,6)->40 (256,8)->32
//   (256)->132+~132agpr=1blk/CU  (256,2)->120, clean, 2blk/CU, 177us.
//   Model: arch cap = (512/min-waves)/2 (even unified split w/ MFMA).
// R13: target 12 waves/CU = (256,3) cap 85.
//   (a) afrag 24 regs -> block LDS (benign identical-value race; own-wave
//       RAW ordered by lgkmcnt). Demand 120-24-pressure ~= 85.
//   (b) I$ compaction: R12 unrolled body ~59 stages ~70-100KB >> 32KB L1I.
//       Roll jx/p/dx2/c loops (#pragma unroll 1, ternary dir ptrs -- no
//       runtime-indexed ptr array -> no scratch). ~12KB code, fits I$.
//   Tripwire: FETCH >> 50MB = spilled; fallback (256,2)+diet.

__device__ __forceinline__ unsigned short f2bf(float f) {
    union { float f; unsigned u; } v; v.f = f;
    unsigned r = v.u + 0x7FFFu + ((v.u >> 16) & 1u);   // RNE
    return (unsigned short)(r >> 16);
}

// direction pointer select without runtime-indexed array (uniform -> SALU)
__device__ __forceinline__ const float* dirptr(int d,
                                               const float* tl, const float* tr,
                                               const float* bl, const float* br)
{
    return (d & 2) ? ((d & 1) ? br : bl) : ((d & 1) ? tr : tl);
}

// lat[b][r] = scale[fo][r] * dot64(f_in[fo][r], xin[b])   (b=0..3, r=0..15)
__device__ __forceinline__ void wlat(const float* __restrict__ f_in,
                                     const float* __restrict__ scale,
                                     int fo,
                                     const float (*xin)[64],   // wave-private LDS [BW][64]
                                     float (*lat)[16],         // wave-private LDS [BW][16]
                                     int lane)
{
    const int bh = lane >> 5;         // batch-within-pass
    const int r  = (lane >> 1) & 15;  // 0..15
    const int h  = lane & 1;          // half of dot
    const float4* fir = (const float4*)(f_in + (size_t)fo * 1024 + r * 64 + h * 32);
    const float   sc  = scale[fo * 16 + r];
#pragma unroll
    for (int bp = 0; bp < BW; bp += 2) {
        const int b = bp + bh;
        const float4* xb = (const float4*)(&xin[b][0] + h * 32);
        float p = 0.f;
#pragma unroll
        for (int i = 0; i < 8; ++i) {
            const float4 a = fir[i], c = xb[i];
            p += a.x * c.x + a.y * c.y + a.z * c.z + a.w * c.w;
        }
        p += __shfl_xor(p, 1);
        if (h == 0) lat[b][r] = p * sc;
    }
}

// xout[b][o] = xin[b][o] + sum_r lat[b][r] * fd[r][o]   (b=0..3)
__device__ __forceinline__ void wchild(const float* __restrict__ fd,
                                       const float (*xin)[64],
                                       const float (*lat)[16],
                                       float (*xout)[64],
                                       int lane)
{
    const int o = lane;
    float f[16];
#pragma unroll
    for (int r = 0; r < 16; ++r) f[r] = fd[r * 64 + o];
#pragma unroll
    for (int b = 0; b < BW; ++b) {
        float acc = xin[b][o];
#pragma unroll
        for (int r = 0; r < 16; ++r) acc += lat[b][r] * f[r];
        xout[b][o] = acc;
    }
}

// leaf rows n = b*8 + nbase (bf16, stride 72 shorts), b=0..3 -> 32 rows
__device__ __forceinline__ void wchild_leaf(const float* __restrict__ fd,
                                            const float (*xin)[64],
                                            const float (*lat)[16],
                                            unsigned short* leaf,   // [32][72]
                                            int nbase,
                                            int lane)
{
    const int o = lane;
    float f[16];
#pragma unroll
    for (int r = 0; r < 16; ++r) f[r] = fd[r * 64 + o];
#pragma unroll
    for (int b = 0; b < BW; ++b) {
        float acc = xin[b][o];
#pragma unroll
        for (int r = 0; r < 16; ++r) acc += lat[b][r] * f[r];
        leaf[(b * 8 + nbase) * 72 + o] = f2bf(acc);
    }
}

// (256,3): 170-reg/wave budget = 85 arch + 85 acc; 3 blocks/CU = 12 waves/CU
__global__ __launch_bounds__(NTHR, 3)
void qtree_kernel(const float* __restrict__ x,      // [128][64]
                  const float* __restrict__ f_in,   // [1365][16][64]
                  const float* __restrict__ f_tl,
                  const float* __restrict__ f_tr,
                  const float* __restrict__ f_bl,
                  const float* __restrict__ f_br,
                  const float* __restrict__ scale,  // [1365][16]
                  const float* __restrict__ head_w, // [48][64]
                  const float* __restrict__ head_b, // [48]
                  float* __restrict__ out)          // [128][3][256][256]
{
    // Per-wave aliased pool, 2304 floats = 9216 B (layout as R8-R12):
    //   [0..1663]  region: A: xa@0 xb@256 | B: leaf[32][72]@0 + x5@1152 | C: sy@0
    //   [1664..2175] x4[2*4][64]   [2176..2239] lat   [2240..2303] lat4
    // Block-shared: s_hb 192B, s_afrag 6144B.
    // Total LDS: 36864 + 192 + 6144 = 43200 B -> 3 blocks/CU = 129.6KB.
    __shared__ __align__(16) float s_pool[4][2304];
    __shared__ float s_hb[48];
    __shared__ short8 s_afrag[384];    // [(mt*2+kc)*64 + lane]

    const int tid  = threadIdx.x;
    const int wv   = tid >> 6;     // wave = 4-batch group
    const int lane = tid & 63;
    const int n    = lane & 15;    // MFMA N index (leaf row in tile)
    const int q    = lane >> 4;    // quad
    const int n3   = blockIdx.x;   // 0..63  level-3 node (y3*8+x3)
    const int bg   = blockIdx.y;   // 0..7   batch group of 16
    const int jy   = blockIdx.z;   // 0..1
    const int y3   = n3 >> 3, x3 = n3 & 7;

    float* P = s_pool[wv];
    float (*xa)[64]  = (float(*)[64])P;            // region phase A
    float (*xb)[64]  = (float(*)[64])(P + 256);
    unsigned short* leaf = (unsigned short*)P;     // region phase B [32][72]
    float (*x5)[64]  = (float(*)[64])(P + 1152);   // region phase B, rows dx2*4+b
    float* sy        = P;                          // region phase C [1536]
    float (*x4)[64]  = (float(*)[64])(P + 1664);   // rows jx*4+b
    float (*lat)[16] = (float(*)[16])(P + 2176);
    float (*lat4)[16]= (float(*)[16])(P + 2240);

    // head bias + head-weight fragments -> LDS.
    // Every wave writes identical values (benign race); a wave's own
    // write-then-read is lgkmcnt-ordered, so no barrier is needed.
    if (lane < 48) s_hb[lane] = head_b[lane];
#pragma unroll
    for (int mt = 0; mt < 3; ++mt)
#pragma unroll
        for (int kc = 0; kc < 2; ++kc) {
            const float* src = head_w + (mt * 16 + n) * 64 + kc * 32 + q * 8;
            short8 a;
#pragma unroll
            for (int j = 0; j < 8; ++j) a[j] = (short)f2bf(src[j]);
            s_afrag[(mt * 2 + kc) * 64 + lane] = a;
        }

    // s_y scatter offsets for tile t=0 (add t*768 at use): leaf n -> (lb, dx2, c)
    // o = mt*16 + q*4 + r; packed 2x16b per u32 (offsets < 1536)
    const int lb = n >> 3, ldx = (n >> 2) & 1, lc = n & 3;
    const int lcy = lc >> 1, lcx = lc & 1;
    const int sy_base = lb * 384 + lcy * 64 + ldx * 8 + lcx * 4;
    unsigned sy_pk[6];
#pragma unroll
    for (int i = 0; i < 6; ++i) {
        unsigned lohi[2];
#pragma unroll
        for (int j = 0; j < 2; ++j) {
            const int t = 2 * i + j;                      // t = mt*4 + r
            const int o = (t >> 2) * 16 + q * 4 + (t & 3);
            lohi[j] = (unsigned)(sy_base + (o % 3) * 128 + (o / 12) * 16 + ((o / 3) & 3));
        }
        sy_pk[i] = lohi[0] | (lohi[1] << 16);
    }

    // load this wave's 4 batches
#pragma unroll
    for (int b = 0; b < BW; ++b)
        xa[b][lane] = x[(size_t)(bg * 16 + wv * 4 + b) * 64 + lane];

    // ---- path L0 -> L1 -> L2 (single child each) ----
    {
        wlat(f_in, scale, 0, xa, lat, lane);
        const int d = ((y3 >> 2) << 1) | (x3 >> 2);
        wchild(dirptr(d, f_tl, f_tr, f_bl, f_br), xa, lat, xb, lane);
    }
    {
        const int fo = 1 + ((y3 >> 2) * 2 + (x3 >> 2));
        wlat(f_in, scale, fo, xb, lat, lane);
        const int d = (((y3 >> 1) & 1) << 1) | ((x3 >> 1) & 1);
        wchild(dirptr(d, f_tl, f_tr, f_bl, f_br) + (size_t)fo * 1024, xb, lat, xa, lane);
    }
    {
        const int fo = 5 + ((y3 >> 1) * 4 + (x3 >> 1));
        wlat(f_in, scale, fo, xa, lat, lane);
        const int d = ((y3 & 1) << 1) | (x3 & 1);
        wchild(dirptr(d, f_tl, f_tr, f_bl, f_br) + (size_t)fo * 1024, xa, lat, xb, lane);
    }
    // ---- L3: children for this jy-half -> x4 (outside aliased region) ----
    {
        const int fo = 21 + n3;
        wlat(f_in, scale, fo, xb, lat, lane);
#pragma unroll 1
        for (int jx = 0; jx < 2; ++jx)
            wchild(dirptr(2 * jy + jx, f_tl, f_tr, f_bl, f_br) + (size_t)fo * 1024,
                   xb, lat, &x4[BW * jx], lane);
    }
    // path xa/xb dead from here; region reused for leaf/x5/sy

    // ---- two L4 subtrees (rolled loops: compact code, fits L1I) ----
#pragma unroll 1
    for (int jx = 0; jx < 2; ++jx) {
        const int y4 = 2 * y3 + jy, x4c = 2 * x3 + jx;
        const int fo4 = 85 + y4 * 16 + x4c;
        wlat(f_in, scale, fo4, &x4[BW * jx], lat4, lane);  // L4 latent persists in lat4

#pragma unroll 1
        for (int p = 0; p < 2; ++p) {
#pragma unroll 1
            for (int dx2 = 0; dx2 < 2; ++dx2)
                wchild(dirptr(2 * p + dx2, f_tl, f_tr, f_bl, f_br) + (size_t)fo4 * 1024,
                       &x4[BW * jx], lat4, &x5[BW * dx2], lane);
#pragma unroll 1
            for (int dx2 = 0; dx2 < 2; ++dx2) {
                const int fo5 = 341 + (2 * y4 + p) * 32 + (2 * x4c + dx2);
                wlat(f_in, scale, fo5, &x5[BW * dx2], lat, lane);
#pragma unroll 1
                for (int c = 0; c < 4; ++c)
                    wchild_leaf(dirptr(c, f_tl, f_tr, f_bl, f_br) + (size_t)fo5 * 1024,
                                &x5[BW * dx2], lat, leaf, dx2 * 4 + c, lane);
            }

            // MFMA head: 32 leaf rows (2 tiles of 16) x 48 outs, K=64
            f32x4 acc[2][3];
#pragma unroll
            for (int t = 0; t < 2; ++t)
#pragma unroll
                for (int mt = 0; mt < 3; ++mt)
                    acc[t][mt] = *(const f32x4*)&s_hb[mt * 16 + q * 4];
#pragma unroll
            for (int kc = 0; kc < 2; ++kc)
#pragma unroll
                for (int t = 0; t < 2; ++t) {
                    const short8 bfrag = *(const short8*)&leaf[(t * 16 + n) * 72 + kc * 32 + q * 8];
#pragma unroll
                    for (int mt = 0; mt < 3; ++mt) {
                        const short8 af = s_afrag[(mt * 2 + kc) * 64 + lane];
                        acc[t][mt] = __builtin_amdgcn_mfma_f32_16x16x32_bf16(af, bfrag, acc[t][mt], 0, 0, 0);
                    }
                }

            // stage y: [4b][3ch][8r][16px]  (sy aliases leaf/x5 -- both dead now)
#pragma unroll
            for (int t = 0; t < 2; ++t)
#pragma unroll
                for (int mt = 0; mt < 3; ++mt)
#pragma unroll
                    for (int r = 0; r < 4; ++r) {
                        const int u = mt * 4 + r;
                        const int ofs = ((sy_pk[u >> 1] >> (16 * (u & 1))) & 0xffff) + t * 768;
                        sy[ofs] = acc[t][mt][r];
                    }

            // full-line stores: rows of 16 px (64 B); 384 float4 chunks = 6/lane
            const int base_row = (4 * y3 + 2 * jy + p) * 8;
            const int base_col = (4 * x3 + 2 * jx) * 8;
#pragma unroll
            for (int s = 0; s < 6; ++s) {
                const int i  = lane + 64 * s;      // 0..383 float4 chunks
                const int c4 = i & 3;
                const int r2 = (i >> 2) & 7;
                const int bc = i >> 5;             // b*3+ch, 0..11
                const float4 v = *(const float4*)&sy[(bc * 8 + r2) * 16 + c4 * 4];
                const size_t off = ((size_t)((bg * 16 + wv * 4 + bc / 3) * 3 + (bc % 3))) * 65536
                                 + (size_t)(base_row + r2) * 256 + base_col + c4 * 4;
                *(float4*)&out[off] = v;
            }
        } // p
    } // jx
}

extern "C" void kernel_launch(void* const* d_in, const int* in_sizes, int n_in,
                              void* d_out, int out_size, void* d_ws, size_t ws_size,
                              hipStream_t stream) {
    const float* x    = (const float*)d_in[0];
    const float* f_in = (const float*)d_in[1];
    const float* f_tl = (const float*)d_in[2];
    const float* f_tr = (const float*)d_in[3];
    const float* f_bl = (const float*)d_in[4];
    const float* f_br = (const float*)d_in[5];
    const float* sc   = (const float*)d_in[6];
    const float* hw   = (const float*)d_in[7];
    const float* hb   = (const float*)d_in[8];
    float* out = (float*)d_out;

    dim3 grid(64, 8, 2);
    qtree_kernel<<<grid, NTHR, 0, stream>>>(x, f_in, f_tl, f_tr, f_bl, f_br, sc, hw, hb, out);
}

// Round 9
// 280.756 us; speedup vs baseline: 1.5365x; 1.5365x over previous
//
#include <hip/hip_runtime.h>

constexpr int NTHR = 256;
constexpr int BW   = 4;      // batches per wave

typedef short  short8 __attribute__((ext_vector_type(8)));  // 8 bf16 (4 VGPRs)
typedef float  f32x4  __attribute__((ext_vector_type(4)));

// factor row offsets per level: L0:0  L1:1  L2:5  L3:21  L4:85  L5:341
// Zero-barrier design: each wave owns BW batches and the whole tree for them.
// All LDS buffers are wave-private (one aliased pool); intra-wave LDS ordering
// is guaranteed by compiler-inserted lgkmcnt waits. No __syncthreads.
//
// Register ledger: (256,3)->80/84 SPILLS at BW=4 (R13: FETCH 155MB),
//   (256,2)->120 clean (R12: FETCH 14.9MB, 177us), (256)->132+agpr=1blk/CU.
//   Model: arch cap = (512/min-waves)/2 (even unified split w/ MFMA).
//   BW=4 arch demand ~120: immovable by +-30 regs -> (256,2) is the point.
// R14: ILP at fixed occupancy. Factor-tile addresses are blockIdx-determined
//   (independent of the data chain) -> explicit 1-ahead ping-pong prefetch
//   (fA/fB, 32 regs) of the fd tiles; paid for by afrag->LDS (-24 regs,
//   correctness proven in R13). ldf issues stage k+1 loads before stage k
//   compute -> tile-load latency hides under wchild/wlat VALU work.
//   Tripwire: FETCH > 60MB = spilled; fallback drops one buffer.

__device__ __forceinline__ unsigned short f2bf(float f) {
    union { float f; unsigned u; } v; v.f = f;
    unsigned r = v.u + 0x7FFFu + ((v.u >> 16) & 1u);   // RNE
    return (unsigned short)(r >> 16);
}

// direction pointer select without runtime-indexed array (no scratch)
__device__ __forceinline__ const float* dirptr(int d,
                                               const float* tl, const float* tr,
                                               const float* bl, const float* br)
{
    return (d & 2) ? ((d & 1) ? br : bl) : ((d & 1) ? tr : tl);
}

// issue the 16 column loads of a fd tile (lane o reads f[r][o], stride 64)
__device__ __forceinline__ void ldf(float f[16], const float* __restrict__ fd, int lane) {
#pragma unroll
    for (int r = 0; r < 16; ++r) f[r] = fd[r * 64 + lane];
}

// lat[b][r] = scale[fo][r] * dot64(f_in[fo][r], xin[b])   (b=0..3, r=0..15)
__device__ __forceinline__ void wlat(const float* __restrict__ f_in,
                                     const float* __restrict__ scale,
                                     int fo,
                                     const float (*xin)[64],   // wave-private LDS [BW][64]
                                     float (*lat)[16],         // wave-private LDS [BW][16]
                                     int lane)
{
    const int bh = lane >> 5;         // batch-within-pass
    const int r  = (lane >> 1) & 15;  // 0..15
    const int h  = lane & 1;          // half of dot
    const float4* fir = (const float4*)(f_in + (size_t)fo * 1024 + r * 64 + h * 32);
    const float   sc  = scale[fo * 16 + r];
#pragma unroll
    for (int bp = 0; bp < BW; bp += 2) {
        const int b = bp + bh;
        const float4* xb = (const float4*)(&xin[b][0] + h * 32);
        float p = 0.f;
#pragma unroll
        for (int i = 0; i < 8; ++i) {
            const float4 a = fir[i], c = xb[i];
            p += a.x * c.x + a.y * c.y + a.z * c.z + a.w * c.w;
        }
        p += __shfl_xor(p, 1);
        if (h == 0) lat[b][r] = p * sc;
    }
}

// xout[b][o] = xin[b][o] + sum_r lat[b][r] * f[r]   (f preloaded by ldf)
__device__ __forceinline__ void wchild_c(const float f[16],
                                         const float (*xin)[64],
                                         const float (*lat)[16],
                                         float (*xout)[64],
                                         int lane)
{
    const int o = lane;
#pragma unroll
    for (int b = 0; b < BW; ++b) {
        float acc = xin[b][o];
#pragma unroll
        for (int r = 0; r < 16; ++r) acc += lat[b][r] * f[r];
        xout[b][o] = acc;
    }
}

// leaf rows n = b*8 + nbase (bf16, stride 72 shorts), b=0..3 -> 32 rows
__device__ __forceinline__ void wchild_leaf_c(const float f[16],
                                              const float (*xin)[64],
                                              const float (*lat)[16],
                                              unsigned short* leaf,   // [32][72]
                                              int nbase,
                                              int lane)
{
    const int o = lane;
#pragma unroll
    for (int b = 0; b < BW; ++b) {
        float acc = xin[b][o];
#pragma unroll
        for (int r = 0; r < 16; ++r) acc += lat[b][r] * f[r];
        leaf[(b * 8 + nbase) * 72 + o] = f2bf(acc);
    }
}

// (256,2): 256-reg/wave budget = 128 arch + 128 acc; 2 blocks/CU (proven clean)
__global__ __launch_bounds__(NTHR, 2)
void qtree_kernel(const float* __restrict__ x,      // [128][64]
                  const float* __restrict__ f_in,   // [1365][16][64]
                  const float* __restrict__ f_tl,
                  const float* __restrict__ f_tr,
                  const float* __restrict__ f_bl,
                  const float* __restrict__ f_br,
                  const float* __restrict__ scale,  // [1365][16]
                  const float* __restrict__ head_w, // [48][64]
                  const float* __restrict__ head_b, // [48]
                  float* __restrict__ out)          // [128][3][256][256]
{
    // Per-wave aliased pool, 2304 floats = 9216 B (layout as R8-R12):
    //   [0..1663]  region: A: xa@0 xb@256 | B: leaf[32][72]@0 + x5@1152 | C: sy@0
    //   [1664..2175] x4[2*4][64]   [2176..2239] lat   [2240..2303] lat4
    // Block-shared: s_hb 192B, s_afrag 6144B.
    // Total LDS: 36864 + 192 + 6144 = 43200 B (2 blocks/CU -> 86.4KB, fits).
    __shared__ __align__(16) float s_pool[4][2304];
    __shared__ float s_hb[48];
    __shared__ short8 s_afrag[384];    // [(mt*2+kc)*64 + lane]

    const int tid  = threadIdx.x;
    const int wv   = tid >> 6;     // wave = 4-batch group
    const int lane = tid & 63;
    const int n    = lane & 15;    // MFMA N index (leaf row in tile)
    const int q    = lane >> 4;    // quad
    const int n3   = blockIdx.x;   // 0..63  level-3 node (y3*8+x3)
    const int bg   = blockIdx.y;   // 0..7   batch group of 16
    const int jy   = blockIdx.z;   // 0..1
    const int y3   = n3 >> 3, x3 = n3 & 7;

    float* P = s_pool[wv];
    float (*xa)[64]  = (float(*)[64])P;            // region phase A
    float (*xb)[64]  = (float(*)[64])(P + 256);
    unsigned short* leaf = (unsigned short*)P;     // region phase B [32][72]
    float (*x5)[64]  = (float(*)[64])(P + 1152);   // region phase B, rows dx2*4+b
    float* sy        = P;                          // region phase C [1536]
    float (*x4)[64]  = (float(*)[64])(P + 1664);   // rows jx*4+b
    float (*lat)[16] = (float(*)[16])(P + 2176);
    float (*lat4)[16]= (float(*)[16])(P + 2240);

    // head bias + head-weight fragments -> LDS.
    // Every wave writes identical values (benign race); own-wave
    // write-then-read is lgkmcnt-ordered, so no barrier is needed.
    if (lane < 48) s_hb[lane] = head_b[lane];
#pragma unroll
    for (int mt = 0; mt < 3; ++mt)
#pragma unroll
        for (int kc = 0; kc < 2; ++kc) {
            const float* src = head_w + (mt * 16 + n) * 64 + kc * 32 + q * 8;
            short8 a;
#pragma unroll
            for (int j = 0; j < 8; ++j) a[j] = (short)f2bf(src[j]);
            s_afrag[(mt * 2 + kc) * 64 + lane] = a;
        }

    // s_y scatter offsets for tile t=0 (add t*768 at use): leaf n -> (lb, dx2, c)
    // o = mt*16 + q*4 + r; packed 2x16b per u32 (offsets < 1536)
    const int lb = n >> 3, ldx = (n >> 2) & 1, lc = n & 3;
    const int lcy = lc >> 1, lcx = lc & 1;
    const int sy_base = lb * 384 + lcy * 64 + ldx * 8 + lcx * 4;
    unsigned sy_pk[6];
#pragma unroll
    for (int i = 0; i < 6; ++i) {
        unsigned lohi[2];
#pragma unroll
        for (int j = 0; j < 2; ++j) {
            const int t = 2 * i + j;                      // t = mt*4 + r
            const int o = (t >> 2) * 16 + q * 4 + (t & 3);
            lohi[j] = (unsigned)(sy_base + (o % 3) * 128 + (o / 12) * 16 + ((o / 3) & 3));
        }
        sy_pk[i] = lohi[0] | (lohi[1] << 16);
    }

    // load this wave's 4 batches
#pragma unroll
    for (int b = 0; b < BW; ++b)
        xa[b][lane] = x[(size_t)(bg * 16 + wv * 4 + b) * 64 + lane];

    float fA[16], fB[16];   // ping-pong prefetch buffers for fd tiles

    // ---- path L0 -> L1 -> L2 (single child each); ldf issued BEFORE wlat ----
    {
        const int d = ((y3 >> 2) << 1) | (x3 >> 2);
        ldf(fA, dirptr(d, f_tl, f_tr, f_bl, f_br), lane);
        wlat(f_in, scale, 0, xa, lat, lane);
        wchild_c(fA, xa, lat, xb, lane);
    }
    {
        const int fo = 1 + ((y3 >> 2) * 2 + (x3 >> 2));
        const int d = (((y3 >> 1) & 1) << 1) | ((x3 >> 1) & 1);
        ldf(fA, dirptr(d, f_tl, f_tr, f_bl, f_br) + (size_t)fo * 1024, lane);
        wlat(f_in, scale, fo, xb, lat, lane);
        wchild_c(fA, xb, lat, xa, lane);
    }
    {
        const int fo = 5 + ((y3 >> 1) * 4 + (x3 >> 1));
        const int d = ((y3 & 1) << 1) | (x3 & 1);
        ldf(fA, dirptr(d, f_tl, f_tr, f_bl, f_br) + (size_t)fo * 1024, lane);
        wlat(f_in, scale, fo, xa, lat, lane);
        wchild_c(fA, xa, lat, xb, lane);
    }
    // ---- L3: both children prefetched, then computed ----
    {
        const int fo = 21 + n3;
        ldf(fA, dirptr(2 * jy + 0, f_tl, f_tr, f_bl, f_br) + (size_t)fo * 1024, lane);
        ldf(fB, dirptr(2 * jy + 1, f_tl, f_tr, f_bl, f_br) + (size_t)fo * 1024, lane);
        wlat(f_in, scale, fo, xb, lat, lane);
        wchild_c(fA, xb, lat, &x4[0], lane);
        wchild_c(fB, xb, lat, &x4[BW], lane);
    }
    // path xa/xb dead from here; region reused for leaf/x5/sy

    // ---- two L4 subtrees ----
    for (int jx = 0; jx < 2; ++jx) {
        const int y4 = 2 * y3 + jy, x4c = 2 * x3 + jx;
        const int fo4 = 85 + y4 * 16 + x4c;
        wlat(f_in, scale, fo4, &x4[BW * jx], lat4, lane);  // L4 latent persists in lat4

        for (int p = 0; p < 2; ++p) {
            // x5 children: prefetch both tiles, then compute
            ldf(fA, dirptr(2 * p + 0, f_tl, f_tr, f_bl, f_br) + (size_t)fo4 * 1024, lane);
            ldf(fB, dirptr(2 * p + 1, f_tl, f_tr, f_bl, f_br) + (size_t)fo4 * 1024, lane);
            wchild_c(fA, &x4[BW * jx], lat4, &x5[0], lane);
            wchild_c(fB, &x4[BW * jx], lat4, &x5[BW], lane);

            const int fo5a = 341 + (2 * y4 + p) * 32 + (2 * x4c + 0);
            const int fo5b = fo5a + 1;

            // ---- dx2=0 leaf burst (ping-pong: next ldf before each compute) ----
            ldf(fA, f_tl + (size_t)fo5a * 1024, lane);              // c=0
            wlat(f_in, scale, fo5a, &x5[0], lat, lane);
            ldf(fB, f_tr + (size_t)fo5a * 1024, lane);              // c=1
            wchild_leaf_c(fA, &x5[0], lat, leaf, 0, lane);
            ldf(fA, f_bl + (size_t)fo5a * 1024, lane);              // c=2
            wchild_leaf_c(fB, &x5[0], lat, leaf, 1, lane);
            ldf(fB, f_br + (size_t)fo5a * 1024, lane);              // c=3
            wchild_leaf_c(fA, &x5[0], lat, leaf, 2, lane);
            ldf(fA, f_tl + (size_t)fo5b * 1024, lane);              // dx2=1 c=0
            wchild_leaf_c(fB, &x5[0], lat, leaf, 3, lane);

            // ---- dx2=1 leaf burst ----
            wlat(f_in, scale, fo5b, &x5[BW], lat, lane);
            ldf(fB, f_tr + (size_t)fo5b * 1024, lane);              // c=1
            wchild_leaf_c(fA, &x5[BW], lat, leaf, 4, lane);
            ldf(fA, f_bl + (size_t)fo5b * 1024, lane);              // c=2
            wchild_leaf_c(fB, &x5[BW], lat, leaf, 5, lane);
            ldf(fB, f_br + (size_t)fo5b * 1024, lane);              // c=3
            wchild_leaf_c(fA, &x5[BW], lat, leaf, 6, lane);
            wchild_leaf_c(fB, &x5[BW], lat, leaf, 7, lane);

            // MFMA head: 32 leaf rows (2 tiles of 16) x 48 outs, K=64
            f32x4 acc[2][3];
#pragma unroll
            for (int t = 0; t < 2; ++t)
#pragma unroll
                for (int mt = 0; mt < 3; ++mt)
                    acc[t][mt] = *(const f32x4*)&s_hb[mt * 16 + q * 4];
#pragma unroll
            for (int kc = 0; kc < 2; ++kc)
#pragma unroll
                for (int t = 0; t < 2; ++t) {
                    const short8 bfrag = *(const short8*)&leaf[(t * 16 + n) * 72 + kc * 32 + q * 8];
#pragma unroll
                    for (int mt = 0; mt < 3; ++mt) {
                        const short8 af = s_afrag[(mt * 2 + kc) * 64 + lane];
                        acc[t][mt] = __builtin_amdgcn_mfma_f32_16x16x32_bf16(af, bfrag, acc[t][mt], 0, 0, 0);
                    }
                }

            // stage y: [4b][3ch][8r][16px]  (sy aliases leaf/x5 -- both dead now)
#pragma unroll
            for (int t = 0; t < 2; ++t)
#pragma unroll
                for (int mt = 0; mt < 3; ++mt)
#pragma unroll
                    for (int r = 0; r < 4; ++r) {
                        const int u = mt * 4 + r;
                        const int ofs = ((sy_pk[u >> 1] >> (16 * (u & 1))) & 0xffff) + t * 768;
                        sy[ofs] = acc[t][mt][r];
                    }

            // full-line stores: rows of 16 px (64 B); 384 float4 chunks = 6/lane
            const int base_row = (4 * y3 + 2 * jy + p) * 8;
            const int base_col = (4 * x3 + 2 * jx) * 8;
#pragma unroll
            for (int s = 0; s < 6; ++s) {
                const int i  = lane + 64 * s;      // 0..383 float4 chunks
                const int c4 = i & 3;
                const int r2 = (i >> 2) & 7;
                const int bc = i >> 5;             // b*3+ch, 0..11
                const float4 v = *(const float4*)&sy[(bc * 8 + r2) * 16 + c4 * 4];
                const size_t off = ((size_t)((bg * 16 + wv * 4 + bc / 3) * 3 + (bc % 3))) * 65536
                                 + (size_t)(base_row + r2) * 256 + base_col + c4 * 4;
                *(float4*)&out[off] = v;
            }
        } // p
    } // jx
}

extern "C" void kernel_launch(void* const* d_in, const int* in_sizes, int n_in,
                              void* d_out, int out_size, void* d_ws, size_t ws_size,
                              hipStream_t stream) {
    const float* x    = (const float*)d_in[0];
    const float* f_in = (const float*)d_in[1];
    const float* f_tl = (const float*)d_in[2];
    const float* f_tr = (const float*)d_in[3];
    const float* f_bl = (const float*)d_in[4];
    const float* f_br = (const float*)d_in[5];
    const float* sc   = (const float*)d_in[6];
    const float* hw   = (const float*)d_in[7];
    const float* hb   = (const float*)d_in[8];
    float* out = (float*)d_out;

    dim3 grid(64, 8, 2);
    qtree_kernel<<<grid, NTHR, 0, stream>>>(x, f_in, f_tl, f_tr, f_bl, f_br, sc, hw, hb, out);
}